// Round 1
// baseline (966.503 us; speedup 1.0000x reference)
//
#include <hip/hip_runtime.h>
#include <cstdint>
#include <cstddef>

// Problem constants
#define B_DIM  8192
#define IN_DIM 2048
#define H_DIM  2048
#define MSZ    (2048 * 2048)   // elements per weight matrix

typedef __attribute__((ext_vector_type(8))) short  short8;   // 8 x bf16 (4 VGPRs)
typedef __attribute__((ext_vector_type(4))) float  float4v;  // MFMA accumulator

__device__ __forceinline__ unsigned short f2bf(float f) {
    union { float f; unsigned u; } v; v.f = f;
    unsigned r = v.u + 0x7fffu + ((v.u >> 16) & 1u);  // RNE
    return (unsigned short)(r >> 16);
}

__device__ __forceinline__ float sigmoidf_(float x) {
    return 1.0f / (1.0f + __expf(-x));
}

#define AS1CV(p) ((const __attribute__((address_space(1))) void*)(p))
#define AS3V(p)  ((__attribute__((address_space(3))) void*)(p))

// ---------------------------------------------------------------------------
// fp32 -> bf16 row-major conversion for x_t and h_prev (blockIdx.z selects)
// ---------------------------------------------------------------------------
__global__ void cvt_rows(const float* __restrict__ x, const float* __restrict__ h,
                         unsigned short* __restrict__ x16,
                         unsigned short* __restrict__ h16) {
    const float* s = blockIdx.z ? h : x;
    unsigned short* d = blockIdx.z ? h16 : x16;
    size_t i = ((size_t)blockIdx.x * blockDim.x + threadIdx.x) * 8;
    float4 a = *(const float4*)(s + i);
    float4 b = *(const float4*)(s + i + 4);
    union { unsigned short us[8]; uint4 u4; } o;
    o.us[0] = f2bf(a.x); o.us[1] = f2bf(a.y); o.us[2] = f2bf(a.z); o.us[3] = f2bf(a.w);
    o.us[4] = f2bf(b.x); o.us[5] = f2bf(b.y); o.us[6] = f2bf(b.z); o.us[7] = f2bf(b.w);
    *(uint4*)(d + i) = o.u4;
}

// ---------------------------------------------------------------------------
// Transpose + convert: W[k][n] fp32 -> Wt[n][k] bf16, for 6 weight matrices
// ---------------------------------------------------------------------------
struct Ptr6 { const float* p[6]; };

__global__ void transpose_cvt(Ptr6 srcs, unsigned short* __restrict__ dst_base) {
    __shared__ float tile[32][33];
    const float* src = srcs.p[blockIdx.z];
    unsigned short* dst = dst_base + (size_t)blockIdx.z * MSZ;
    int x = blockIdx.x * 32 + threadIdx.x;   // col n (coalesced read)
    int y = blockIdx.y * 32 + threadIdx.y;   // row k
#pragma unroll
    for (int j = 0; j < 32; j += 8)
        tile[threadIdx.y + j][threadIdx.x] = src[(size_t)(y + j) * H_DIM + x];
    __syncthreads();
    int x2 = blockIdx.y * 32 + threadIdx.x;  // col k (coalesced write)
    int y2 = blockIdx.x * 32 + threadIdx.y;  // row n
#pragma unroll
    for (int j = 0; j < 32; j += 8)
        dst[(size_t)(y2 + j) * IN_DIM + x2] = f2bf(tile[threadIdx.x][threadIdx.y + j]);
}

// ---------------------------------------------------------------------------
// GEMM core (m97 recipe): 128x128 tile, BK=32, 16x16x32 bf16 MFMA, 4x4/wave.
// A: [m][k] bf16 row-major stride 2048; Bt: [n][k] bf16 row-major stride 2048.
// Accumulates one 2048-deep K panel (64 iterations of BK=32).
// ---------------------------------------------------------------------------
__device__ __forceinline__ void gemm_panel(const unsigned short* __restrict__ A,
                                           const unsigned short* __restrict__ Bt,
                                           int m0, int nb,
                                           float4v (&acc)[4][4],
                                           unsigned short* lds) {
    unsigned short* Al = lds;            // [128][32]  (8 KB)
    unsigned short* Bl = lds + 128 * 32; // [128][32]  (8 KB)
    const int t    = threadIdx.x;
    const int lane = t & 63;
    const int wm   = (t >> 6) >> 1;
    const int wn   = (t >> 6) & 1;
    const int row  = t >> 2;   // 0..63
    const int seg  = t & 3;    // 16B segment within a 64B row
    const int fr   = lane & 15;
    const int fs   = (lane >> 4) * 8;

    for (int kb = 0; kb < 64; ++kb) {
        const int k0 = kb * 32;
        __syncthreads();  // prev iter's LDS reads complete before overwrite
#pragma unroll
        for (int c = 0; c < 2; ++c) {
            const unsigned short* ga = A  + (size_t)(m0 + c * 64 + row) * 2048 + k0 + seg * 8;
            const unsigned short* gb = Bt + (size_t)(nb + c * 64 + row) * 2048 + k0 + seg * 8;
            __builtin_amdgcn_global_load_lds(AS1CV(ga), AS3V(Al + c * 2048 + t * 8), 16, 0, 0);
            __builtin_amdgcn_global_load_lds(AS1CV(gb), AS3V(Bl + c * 2048 + t * 8), 16, 0, 0);
        }
        __syncthreads();  // compiler emits vmcnt(0) drain: staging complete

        short8 af[4], bfr[4];
#pragma unroll
        for (int i = 0; i < 4; ++i)
            af[i] = *(const short8*)(Al + (wm * 64 + i * 16 + fr) * 32 + fs);
#pragma unroll
        for (int j = 0; j < 4; ++j)
            bfr[j] = *(const short8*)(Bl + (wn * 64 + j * 16 + fr) * 32 + fs);
#pragma unroll
        for (int i = 0; i < 4; ++i)
#pragma unroll
            for (int j = 0; j < 4; ++j)
                acc[i][j] = __builtin_amdgcn_mfma_f32_16x16x32_bf16(af[i], bfr[j], acc[i][j], 0, 0, 0);
    }
}

// ---------------------------------------------------------------------------
// GEMM 1: [x|h] @ [[Wz;Uz] | [Wr;Ur]]  -> z to d_out (fp32), r*h to ws (bf16)
// grid (32, 64): x = N-tile over 4096 cols (z half then r half), y = M-tile
// ---------------------------------------------------------------------------
__global__ __launch_bounds__(256) void gemm_zr(const unsigned short* __restrict__ x16,
                                               const unsigned short* __restrict__ h16,
                                               const unsigned short* __restrict__ wt,
                                               const float* __restrict__ hprev,
                                               const float* __restrict__ bz,
                                               const float* __restrict__ br,
                                               float* __restrict__ zout,
                                               unsigned short* __restrict__ rh16) {
    __shared__ unsigned short lds[2 * 128 * 32];
    float4v acc[4][4];
#pragma unroll
    for (int i = 0; i < 4; ++i)
#pragma unroll
        for (int j = 0; j < 4; ++j)
            acc[i][j] = (float4v){0.f, 0.f, 0.f, 0.f};

    const int m0 = blockIdx.y * 128;
    const int nB = blockIdx.x * 128;         // 0..4095
    const bool zhalf = nB < 2048;
    const int nb = zhalf ? nB : nB - 2048;   // base row within the 2048-wide half
    const unsigned short* B0 = zhalf ? (wt + 0 * (size_t)MSZ) : (wt + 1 * (size_t)MSZ); // WzT / WrT
    const unsigned short* B1 = zhalf ? (wt + 3 * (size_t)MSZ) : (wt + 4 * (size_t)MSZ); // UzT / UrT

    gemm_panel(x16, B0, m0, nb, acc, lds);   // k in [0, 2048)
    gemm_panel(h16, B1, m0, nb, acc, lds);   // k in [2048, 4096)

    const int t = threadIdx.x, lane = t & 63;
    const int wm = (t >> 6) >> 1, wn = (t >> 6) & 1;
    const int col = lane & 15, rbase = (lane >> 4) * 4;
#pragma unroll
    for (int i = 0; i < 4; ++i)
#pragma unroll
        for (int j = 0; j < 4; ++j) {
            const int gn = nb + wn * 64 + j * 16 + col;        // col within the half
            const int gm0 = m0 + wm * 64 + i * 16 + rbase;
            if (zhalf) {
                const float bias = bz[gn];
#pragma unroll
                for (int r = 0; r < 4; ++r) {
                    const size_t idx = (size_t)(gm0 + r) * H_DIM + gn;
                    zout[idx] = sigmoidf_(acc[i][j][r] + bias);
                }
            } else {
                const float bias = br[gn];
#pragma unroll
                for (int r = 0; r < 4; ++r) {
                    const size_t idx = (size_t)(gm0 + r) * H_DIM + gn;
                    const float rt = sigmoidf_(acc[i][j][r] + bias);
                    rh16[idx] = f2bf(rt * hprev[idx]);
                }
            }
        }
}

// ---------------------------------------------------------------------------
// GEMM 2: [x|r*h] @ [Wh;Uh] -> h_t = (1-z)h + z*tanh(.+bh), overwrite d_out
// grid (16, 64)
// ---------------------------------------------------------------------------
__global__ __launch_bounds__(256) void gemm_h(const unsigned short* __restrict__ x16,
                                              const unsigned short* __restrict__ rh16,
                                              const unsigned short* __restrict__ WhT,
                                              const unsigned short* __restrict__ UhT,
                                              const float* __restrict__ hprev,
                                              const float* __restrict__ bh,
                                              float* __restrict__ out) {
    __shared__ unsigned short lds[2 * 128 * 32];
    float4v acc[4][4];
#pragma unroll
    for (int i = 0; i < 4; ++i)
#pragma unroll
        for (int j = 0; j < 4; ++j)
            acc[i][j] = (float4v){0.f, 0.f, 0.f, 0.f};

    const int m0 = blockIdx.y * 128;
    const int nb = blockIdx.x * 128;

    gemm_panel(x16,  WhT, m0, nb, acc, lds);
    gemm_panel(rh16, UhT, m0, nb, acc, lds);

    const int t = threadIdx.x, lane = t & 63;
    const int wm = (t >> 6) >> 1, wn = (t >> 6) & 1;
    const int col = lane & 15, rbase = (lane >> 4) * 4;
#pragma unroll
    for (int i = 0; i < 4; ++i)
#pragma unroll
        for (int j = 0; j < 4; ++j) {
            const int gn = nb + wn * 64 + j * 16 + col;
            const int gm0 = m0 + wm * 64 + i * 16 + rbase;
            const float bias = bh[gn];
#pragma unroll
            for (int r = 0; r < 4; ++r) {
                const size_t idx = (size_t)(gm0 + r) * H_DIM + gn;
                const float ht = tanhf(acc[i][j][r] + bias);
                const float z = out[idx];     // z was staged here by gemm_zr
                const float h = hprev[idx];
                out[idx] = (1.0f - z) * h + z * ht;
            }
        }
}

// ---------------------------------------------------------------------------
// Workspace layout (needs 144 MB):
//   [0,   32MB)  x16    8192x2048 bf16
//   [32,  64MB)  h16    8192x2048 bf16
//   [64, 112MB)  wt     6 x 2048x2048 bf16 transposed: WzT WrT WhT UzT UrT UhT
//   [112,144MB)  rh16   8192x2048 bf16
// ---------------------------------------------------------------------------
extern "C" void kernel_launch(void* const* d_in, const int* in_sizes, int n_in,
                              void* d_out, int out_size, void* d_ws, size_t ws_size,
                              hipStream_t stream) {
    const float* x  = (const float*)d_in[0];
    const float* h  = (const float*)d_in[1];
    const float* Wz = (const float*)d_in[2];
    const float* Wr = (const float*)d_in[3];
    const float* Wh = (const float*)d_in[4];
    const float* Uz = (const float*)d_in[5];
    const float* Ur = (const float*)d_in[6];
    const float* Uh = (const float*)d_in[7];
    const float* bz = (const float*)d_in[8];
    const float* br = (const float*)d_in[9];
    const float* bh = (const float*)d_in[10];
    float* out = (float*)d_out;

    char* ws = (char*)d_ws;
    unsigned short* x16  = (unsigned short*)(ws);
    unsigned short* h16  = (unsigned short*)(ws + (size_t)32 * 1024 * 1024);
    unsigned short* wt   = (unsigned short*)(ws + (size_t)64 * 1024 * 1024);
    unsigned short* rh16 = (unsigned short*)(ws + (size_t)112 * 1024 * 1024);

    // 1) convert x, h to bf16 (16.7M elems each, 8/thread)
    cvt_rows<<<dim3(B_DIM * IN_DIM / 8 / 256, 1, 2), 256, 0, stream>>>(x, h, x16, h16);

    // 2) transpose+convert the 6 weights to [n][k] bf16
    Ptr6 p6; p6.p[0] = Wz; p6.p[1] = Wr; p6.p[2] = Wh; p6.p[3] = Uz; p6.p[4] = Ur; p6.p[5] = Uh;
    transpose_cvt<<<dim3(64, 64, 6), dim3(32, 8), 0, stream>>>(p6, wt);

    // 3) z/r GEMM (M=8192, N=4096, K=4096)
    gemm_zr<<<dim3(32, 64), 256, 0, stream>>>(x16, h16, wt, h, bz, br, out, rh16);

    // 4) candidate GEMM + final gate (M=8192, N=2048, K=4096)
    gemm_h<<<dim3(16, 64), 256, 0, stream>>>(x16, rh16, wt + 2 * (size_t)MSZ,
                                             wt + 5 * (size_t)MSZ, h, bh, out);
}

// Round 2
// 909.562 us; speedup vs baseline: 1.0626x; 1.0626x over previous
//
#include <hip/hip_runtime.h>
#include <cstdint>
#include <cstddef>

// Problem constants
#define B_DIM  8192
#define H_DIM  2048
#define LDA    6144      // A buffer column stride: [h | x | rh]
#define LDB    4096      // B buffers column stride (K=4096 concatenated)

typedef __attribute__((ext_vector_type(8))) short  short8;   // 8 x bf16 (4 VGPRs)
typedef __attribute__((ext_vector_type(4))) float  float4v;  // MFMA accumulator

__device__ __forceinline__ unsigned short f2bf(float f) {
    union { float f; unsigned u; } v; v.f = f;
    unsigned r = v.u + 0x7fffu + ((v.u >> 16) & 1u);  // RNE
    return (unsigned short)(r >> 16);
}

__device__ __forceinline__ float sigmoidf_(float x) {
    return 1.0f / (1.0f + __expf(-x));
}

#define AS1CV(p) ((const __attribute__((address_space(1))) void*)(p))
#define AS3V(p)  ((__attribute__((address_space(3))) void*)(p))

// ---------------------------------------------------------------------------
// fp32 -> bf16 conversion of x_t / h_prev into the fused A buffer.
// A[row][0..2048)=h, A[row][2048..4096)=x. One block per row (256 thr x 8 elem).
// ---------------------------------------------------------------------------
__global__ void cvt_rows(const float* __restrict__ x, const float* __restrict__ h,
                         unsigned short* __restrict__ Abuf) {
    const float* s = blockIdx.z ? h : x;
    const int coff = blockIdx.z ? 0 : 2048;
    const int row = blockIdx.x;
    const int c = threadIdx.x * 8;
    float4 a = *(const float4*)(s + (size_t)row * 2048 + c);
    float4 b = *(const float4*)(s + (size_t)row * 2048 + c + 4);
    union { unsigned short us[8]; uint4 u4; } o;
    o.us[0] = f2bf(a.x); o.us[1] = f2bf(a.y); o.us[2] = f2bf(a.z); o.us[3] = f2bf(a.w);
    o.us[4] = f2bf(b.x); o.us[5] = f2bf(b.y); o.us[6] = f2bf(b.z); o.us[7] = f2bf(b.w);
    *(uint4*)(Abuf + (size_t)row * LDA + coff + c) = o.u4;
}

// ---------------------------------------------------------------------------
// Transpose + convert: src fp32 [2048 k][2048 n] -> dst bf16 [n][k], dst row
// stride 4096 (slot within a concatenated-K B buffer). 64x64 tiles.
// ---------------------------------------------------------------------------
struct P6 { const float* s[6]; unsigned short* d[6]; };

__global__ void transpose_cvt(P6 io) {
    __shared__ float tile[64][65];
    const float* src = io.s[blockIdx.z];
    unsigned short* dst = io.d[blockIdx.z];
    const int n0 = blockIdx.x * 64;
    const int k0 = blockIdx.y * 64;
    const int t = threadIdx.x;
#pragma unroll
    for (int p = 0; p < 4; ++p) {
        const int k = p * 16 + (t >> 4);
        const int n4 = (t & 15) * 4;
        float4 v = *(const float4*)(src + (size_t)(k0 + k) * 2048 + n0 + n4);
        tile[n4 + 0][k] = v.x; tile[n4 + 1][k] = v.y;
        tile[n4 + 2][k] = v.z; tile[n4 + 3][k] = v.w;
    }
    __syncthreads();
#pragma unroll
    for (int p = 0; p < 2; ++p) {
        const int n = p * 32 + (t >> 3);
        const int k8 = (t & 7) * 8;
        union { unsigned short us[8]; uint4 u4; } o;
#pragma unroll
        for (int q = 0; q < 8; ++q) o.us[q] = f2bf(tile[n][k8 + q]);
        *(uint4*)(dst + (size_t)(n0 + n) * LDB + k0 + k8) = o.u4;
    }
}

// ---------------------------------------------------------------------------
// GEMM core: m97 recipe + XOR-swizzled LDS. 128x128 tile, BK=32, single
// 128-iteration K-loop (K=4096). A [m][k] stride LDA, Bt [n][k] stride LDB.
// LDS slot p (16B) of row r holds global segment p ^ ((r>>1)&3) -> fragment
// reads spread over all 8 bank-quarters per 16-lane phase (no conflicts).
// ---------------------------------------------------------------------------
__device__ __forceinline__ void gemm_core(const unsigned short* __restrict__ A,
                                          const unsigned short* __restrict__ Bt,
                                          int m0, int n0,
                                          float4v (&acc)[4][4],
                                          unsigned short* lds) {
    unsigned short* Al = lds;            // [128][32]
    unsigned short* Bl = lds + 128 * 32; // [128][32]
    const int t    = threadIdx.x;
    const int lane = t & 63;
    const int wm   = (t >> 6) >> 1;
    const int wn   = (t >> 6) & 1;
    const int row  = t >> 2;                                  // staging row 0..63
    const int sseg = (((t & 3) ^ ((t >> 3) & 3))) * 8;        // swizzled k-seg (elems)
    const int fr   = lane & 15;
    const int fsw  = (((lane >> 4) ^ ((fr >> 1) & 3))) * 8;   // swizzled frag k-offset

    const unsigned short* Ab = A + (size_t)(m0 + row) * LDA + sseg;
    const unsigned short* Bb = Bt + (size_t)(n0 + row) * LDB + sseg;

    for (int kb = 0; kb < 128; ++kb) {
        const int k0 = kb * 32;
        __syncthreads();  // prev iter's LDS reads complete before overwrite
        __builtin_amdgcn_global_load_lds(AS1CV(Ab + k0),                  AS3V(Al + t * 8), 16, 0, 0);
        __builtin_amdgcn_global_load_lds(AS1CV(Ab + (size_t)64 * LDA + k0), AS3V(Al + 2048 + t * 8), 16, 0, 0);
        __builtin_amdgcn_global_load_lds(AS1CV(Bb + k0),                  AS3V(Bl + t * 8), 16, 0, 0);
        __builtin_amdgcn_global_load_lds(AS1CV(Bb + (size_t)64 * LDB + k0), AS3V(Bl + 2048 + t * 8), 16, 0, 0);
        __syncthreads();  // staging complete

        short8 af[4], bfr[4];
#pragma unroll
        for (int i = 0; i < 4; ++i)
            af[i] = *(const short8*)(Al + (wm * 64 + i * 16 + fr) * 32 + fsw);
#pragma unroll
        for (int j = 0; j < 4; ++j)
            bfr[j] = *(const short8*)(Bl + (wn * 64 + j * 16 + fr) * 32 + fsw);
#pragma unroll
        for (int i = 0; i < 4; ++i)
#pragma unroll
            for (int j = 0; j < 4; ++j)
                acc[i][j] = __builtin_amdgcn_mfma_f32_16x16x32_bf16(af[i], bfr[j], acc[i][j], 0, 0, 0);
    }
}

// ---------------------------------------------------------------------------
// GEMM 1: A(k-window [h|x]) @ Bzr([Uz;Wz] rows 0..2047 | [Ur;Wr] rows 2048..4095)
// n<2048 half: z = sigmoid(.+bz) -> d_out.  n>=2048: r=sigmoid(.+br),
// write r*h_prev bf16 into A's rh column block. grid (32, 64).
// ---------------------------------------------------------------------------
__global__ __launch_bounds__(256) void gemm_zr(const unsigned short* __restrict__ Abuf,
                                               const unsigned short* __restrict__ Bzr,
                                               const float* __restrict__ hprev,
                                               const float* __restrict__ bz,
                                               const float* __restrict__ br,
                                               float* __restrict__ zout,
                                               unsigned short* __restrict__ Arh) {
    __shared__ unsigned short lds[2 * 128 * 32];
    float4v acc[4][4];
#pragma unroll
    for (int i = 0; i < 4; ++i)
#pragma unroll
        for (int j = 0; j < 4; ++j)
            acc[i][j] = (float4v){0.f, 0.f, 0.f, 0.f};

    const int m0 = blockIdx.y * 128;
    const int n0 = blockIdx.x * 128;        // 0..4095 across [z | r]

    gemm_core(Abuf, Bzr, m0, n0, acc, lds); // K = 4096 = [h | x]

    const int t = threadIdx.x, lane = t & 63;
    const int wm = (t >> 6) >> 1, wn = (t >> 6) & 1;
    const int col = lane & 15, rbase = (lane >> 4) * 4;
    const bool zhalf = n0 < 2048;
#pragma unroll
    for (int i = 0; i < 4; ++i)
#pragma unroll
        for (int j = 0; j < 4; ++j) {
            const int gn = n0 + wn * 64 + j * 16 + col;
            const int gm0 = m0 + wm * 64 + i * 16 + rbase;
            if (zhalf) {
                const float bias = bz[gn];
#pragma unroll
                for (int r = 0; r < 4; ++r) {
                    const size_t idx = (size_t)(gm0 + r) * H_DIM + gn;
                    zout[idx] = sigmoidf_(acc[i][j][r] + bias);
                }
            } else {
                const int gn2 = gn - 2048;
                const float bias = br[gn2];
#pragma unroll
                for (int r = 0; r < 4; ++r) {
                    const size_t idx = (size_t)(gm0 + r) * H_DIM + gn2;
                    const float rt = sigmoidf_(acc[i][j][r] + bias);
                    Arh[(size_t)(gm0 + r) * LDA + gn2] = f2bf(rt * hprev[idx]);
                }
            }
        }
}

// ---------------------------------------------------------------------------
// GEMM 2: A(k-window [x|rh]) @ Bh([Wh;Uh]) -> h_t = (1-z)h + z*tanh(.+bh).
// grid (16, 64).
// ---------------------------------------------------------------------------
__global__ __launch_bounds__(256) void gemm_h(const unsigned short* __restrict__ Axrh,
                                              const unsigned short* __restrict__ Bh,
                                              const float* __restrict__ hprev,
                                              const float* __restrict__ bh,
                                              float* __restrict__ out) {
    __shared__ unsigned short lds[2 * 128 * 32];
    float4v acc[4][4];
#pragma unroll
    for (int i = 0; i < 4; ++i)
#pragma unroll
        for (int j = 0; j < 4; ++j)
            acc[i][j] = (float4v){0.f, 0.f, 0.f, 0.f};

    const int m0 = blockIdx.y * 128;
    const int n0 = blockIdx.x * 128;

    gemm_core(Axrh, Bh, m0, n0, acc, lds);  // K = 4096 = [x | rh]

    const int t = threadIdx.x, lane = t & 63;
    const int wm = (t >> 6) >> 1, wn = (t >> 6) & 1;
    const int col = lane & 15, rbase = (lane >> 4) * 4;
#pragma unroll
    for (int i = 0; i < 4; ++i)
#pragma unroll
        for (int j = 0; j < 4; ++j) {
            const int gn = n0 + wn * 64 + j * 16 + col;
            const int gm0 = m0 + wm * 64 + i * 16 + rbase;
            const float bias = bh[gn];
#pragma unroll
            for (int r = 0; r < 4; ++r) {
                const size_t idx = (size_t)(gm0 + r) * H_DIM + gn;
                const float ht = tanhf(acc[i][j][r] + bias);
                const float z = out[idx];     // z staged here by gemm_zr
                const float h = hprev[idx];
                out[idx] = (1.0f - z) * h + z * ht;
            }
        }
}

// ---------------------------------------------------------------------------
// Workspace (exactly 144 MiB):
//   [0,    96MiB)  A    8192 x 6144 bf16 : cols [0,2048)=h16, [2048,4096)=x16,
//                                          [4096,6144)=rh16 (filled by gemm_zr)
//   [96,  128MiB)  Bzr  4096 x 4096 bf16 : rows n:   [UzT(n)|WzT(n)]
//                                          rows 2048+n: [UrT(n)|WrT(n)]
//   [128, 144MiB)  Bh   2048 x 4096 bf16 : rows n: [WhT(n)|UhT(n)]
// ---------------------------------------------------------------------------
extern "C" void kernel_launch(void* const* d_in, const int* in_sizes, int n_in,
                              void* d_out, int out_size, void* d_ws, size_t ws_size,
                              hipStream_t stream) {
    const float* x  = (const float*)d_in[0];
    const float* h  = (const float*)d_in[1];
    const float* Wz = (const float*)d_in[2];
    const float* Wr = (const float*)d_in[3];
    const float* Wh = (const float*)d_in[4];
    const float* Uz = (const float*)d_in[5];
    const float* Ur = (const float*)d_in[6];
    const float* Uh = (const float*)d_in[7];
    const float* bz = (const float*)d_in[8];
    const float* br = (const float*)d_in[9];
    const float* bh = (const float*)d_in[10];
    float* out = (float*)d_out;

    char* ws = (char*)d_ws;
    unsigned short* Abuf = (unsigned short*)(ws);
    unsigned short* Bzr  = (unsigned short*)(ws + (size_t)96  * 1024 * 1024);
    unsigned short* Bh   = (unsigned short*)(ws + (size_t)128 * 1024 * 1024);

    // 1) convert x, h into fused A buffer
    cvt_rows<<<dim3(B_DIM, 1, 2), 256, 0, stream>>>(x, h, Abuf);

    // 2) transpose+convert weights into concatenated-K B buffers
    P6 io;
    io.s[0] = Uz; io.d[0] = Bzr;                                   // rows 0..2047, k 0..2047
    io.s[1] = Wz; io.d[1] = Bzr + 2048;                            // rows 0..2047, k 2048..4095
    io.s[2] = Ur; io.d[2] = Bzr + (size_t)2048 * LDB;              // rows 2048..4095
    io.s[3] = Wr; io.d[3] = Bzr + (size_t)2048 * LDB + 2048;
    io.s[4] = Wh; io.d[4] = Bh;
    io.s[5] = Uh; io.d[5] = Bh + 2048;
    transpose_cvt<<<dim3(32, 32, 6), 256, 0, stream>>>(io);

    // 3) z/r GEMM: M=8192, N=4096, K=4096
    gemm_zr<<<dim3(32, 64), 256, 0, stream>>>(Abuf, Bzr, h, bz, br, out,
                                              Abuf + 4096 /* rh col block */);

    // 4) candidate GEMM + final gate: M=8192, N=2048, K=4096
    gemm_h<<<dim3(16, 64), 256, 0, stream>>>(Abuf + 2048 /* [x|rh] window */,
                                             Bh, h, bh, out);
}

// Round 3
// 882.286 us; speedup vs baseline: 1.0955x; 1.0309x over previous
//
#include <hip/hip_runtime.h>
#include <cstdint>
#include <cstddef>

// Problem constants
#define B_DIM  8192
#define H_DIM  2048
#define LDA    6144      // A buffer column stride: [h | x | rh]
#define LDB    4096      // B buffers column stride (K=4096 concatenated)

typedef __attribute__((ext_vector_type(8))) short  short8;   // 8 x bf16 (4 VGPRs)
typedef __attribute__((ext_vector_type(4))) float  float4v;  // MFMA accumulator

__device__ __forceinline__ unsigned short f2bf(float f) {
    union { float f; unsigned u; } v; v.f = f;
    unsigned r = v.u + 0x7fffu + ((v.u >> 16) & 1u);  // RNE
    return (unsigned short)(r >> 16);
}

__device__ __forceinline__ float sigmoidf_(float x) {
    return 1.0f / (1.0f + __expf(-x));
}

#define AS1CV(p) ((const __attribute__((address_space(1))) void*)(p))
#define AS3V(p)  ((__attribute__((address_space(3))) void*)(p))

// ---------------------------------------------------------------------------
// fp32 -> bf16 conversion of x_t / h_prev into the fused A buffer.
// A[row][0..2048)=h, A[row][2048..4096)=x. One block per row (256 thr x 8 elem).
// ---------------------------------------------------------------------------
__global__ void cvt_rows(const float* __restrict__ x, const float* __restrict__ h,
                         unsigned short* __restrict__ Abuf) {
    const float* s = blockIdx.z ? h : x;
    const int coff = blockIdx.z ? 0 : 2048;
    const int row = blockIdx.x;
    const int c = threadIdx.x * 8;
    float4 a = *(const float4*)(s + (size_t)row * 2048 + c);
    float4 b = *(const float4*)(s + (size_t)row * 2048 + c + 4);
    union { unsigned short us[8]; uint4 u4; } o;
    o.us[0] = f2bf(a.x); o.us[1] = f2bf(a.y); o.us[2] = f2bf(a.z); o.us[3] = f2bf(a.w);
    o.us[4] = f2bf(b.x); o.us[5] = f2bf(b.y); o.us[6] = f2bf(b.z); o.us[7] = f2bf(b.w);
    *(uint4*)(Abuf + (size_t)row * LDA + coff + c) = o.u4;
}

// ---------------------------------------------------------------------------
// Transpose + convert: src fp32 [2048 k][2048 n] -> dst bf16 [n][k], dst row
// stride 4096 (slot within a concatenated-K B buffer). 64x64 tiles.
// ---------------------------------------------------------------------------
struct P6 { const float* s[6]; unsigned short* d[6]; };

__global__ void transpose_cvt(P6 io) {
    __shared__ float tile[64][65];
    const float* src = io.s[blockIdx.z];
    unsigned short* dst = io.d[blockIdx.z];
    const int n0 = blockIdx.x * 64;
    const int k0 = blockIdx.y * 64;
    const int t = threadIdx.x;
#pragma unroll
    for (int p = 0; p < 4; ++p) {
        const int k = p * 16 + (t >> 4);
        const int n4 = (t & 15) * 4;
        float4 v = *(const float4*)(src + (size_t)(k0 + k) * 2048 + n0 + n4);
        tile[n4 + 0][k] = v.x; tile[n4 + 1][k] = v.y;
        tile[n4 + 2][k] = v.z; tile[n4 + 3][k] = v.w;
    }
    __syncthreads();
#pragma unroll
    for (int p = 0; p < 2; ++p) {
        const int n = p * 32 + (t >> 3);
        const int k8 = (t & 7) * 8;
        union { unsigned short us[8]; uint4 u4; } o;
#pragma unroll
        for (int q = 0; q < 8; ++q) o.us[q] = f2bf(tile[n][k8 + q]);
        *(uint4*)(dst + (size_t)(n0 + n) * LDB + k0 + k8) = o.u4;
    }
}

// ---------------------------------------------------------------------------
// GEMM core: 128x128 tile, BK=32, 16x16x32 bf16 MFMA, 4x4 acc/wave,
// XOR-swizzled LDS (0 bank conflicts), DOUBLE-BUFFERED staging:
// stage(kb+1) issues right after the barrier, compute(kb) runs on the other
// buffer, so the barrier's vmcnt(0) drain lands after a full compute phase.
// ---------------------------------------------------------------------------
__device__ __forceinline__ void stage_tile(const unsigned short* __restrict__ Ab,
                                           const unsigned short* __restrict__ Bb,
                                           unsigned short* buf, int t, int k0) {
    // buf layout: A [0,4096) elems, B [4096,8192) elems  (8KB each)
    __builtin_amdgcn_global_load_lds(AS1CV(Ab + k0),                    AS3V(buf + t * 8),        16, 0, 0);
    __builtin_amdgcn_global_load_lds(AS1CV(Ab + (size_t)64 * LDA + k0), AS3V(buf + 2048 + t * 8), 16, 0, 0);
    __builtin_amdgcn_global_load_lds(AS1CV(Bb + k0),                    AS3V(buf + 4096 + t * 8), 16, 0, 0);
    __builtin_amdgcn_global_load_lds(AS1CV(Bb + (size_t)64 * LDB + k0), AS3V(buf + 6144 + t * 8), 16, 0, 0);
}

__device__ __forceinline__ void gemm_core(const unsigned short* __restrict__ A,
                                          const unsigned short* __restrict__ Bt,
                                          int m0, int n0,
                                          float4v (&acc)[4][4],
                                          unsigned short* lds) {
    const int t    = threadIdx.x;
    const int lane = t & 63;
    const int wm   = (t >> 6) >> 1;
    const int wn   = (t >> 6) & 1;
    const int row  = t >> 2;                                  // staging row 0..63
    const int sseg = (((t & 3) ^ ((t >> 3) & 3))) * 8;        // swizzled k-seg (elems)
    const int fr   = lane & 15;
    const int fsw  = (((lane >> 4) ^ ((fr >> 1) & 3))) * 8;   // swizzled frag k-offset

    const unsigned short* Ab = A  + (size_t)(m0 + row) * LDA + sseg;
    const unsigned short* Bb = Bt + (size_t)(n0 + row) * LDB + sseg;

    stage_tile(Ab, Bb, lds, t, 0);   // prologue: tile 0 into buf 0

#pragma unroll 2
    for (int kb = 0; kb < 128; ++kb) {
        const int cur = kb & 1;
        unsigned short* bufc = lds + cur * 8192;
        __syncthreads();  // drains stage(kb) [issued last iter]; publishes buf[cur]
        if (kb + 1 < 128)
            stage_tile(Ab, Bb, lds + (cur ^ 1) * 8192, t, (kb + 1) * 32);

        short8 af[4], bfr[4];
#pragma unroll
        for (int i = 0; i < 4; ++i)
            af[i] = *(const short8*)(bufc + (wm * 64 + i * 16 + fr) * 32 + fsw);
#pragma unroll
        for (int j = 0; j < 4; ++j)
            bfr[j] = *(const short8*)(bufc + 4096 + (wn * 64 + j * 16 + fr) * 32 + fsw);
#pragma unroll
        for (int i = 0; i < 4; ++i)
#pragma unroll
            for (int j = 0; j < 4; ++j)
                acc[i][j] = __builtin_amdgcn_mfma_f32_16x16x32_bf16(af[i], bfr[j], acc[i][j], 0, 0, 0);
    }
}

// ---------------------------------------------------------------------------
// GEMM 1: A(k-window [h|x]) @ Bzr([Uz;Wz] | [Ur;Wr]) -> z (fp32) to d_out,
// r*h_prev (bf16) into A's rh column block. grid (32, 64).
// ---------------------------------------------------------------------------
__global__ __launch_bounds__(256) void gemm_zr(const unsigned short* __restrict__ Abuf,
                                               const unsigned short* __restrict__ Bzr,
                                               const float* __restrict__ hprev,
                                               const float* __restrict__ bz,
                                               const float* __restrict__ br,
                                               float* __restrict__ zout,
                                               unsigned short* __restrict__ Arh) {
    __shared__ unsigned short lds[4 * 128 * 32];   // 2 x (A 8KB + B 8KB)
    float4v acc[4][4];
#pragma unroll
    for (int i = 0; i < 4; ++i)
#pragma unroll
        for (int j = 0; j < 4; ++j)
            acc[i][j] = (float4v){0.f, 0.f, 0.f, 0.f};

    const int m0 = blockIdx.y * 128;
    const int n0 = blockIdx.x * 128;        // 0..4095 across [z | r]

    gemm_core(Abuf, Bzr, m0, n0, acc, lds); // K = 4096 = [h | x]

    const int t = threadIdx.x, lane = t & 63;
    const int wm = (t >> 6) >> 1, wn = (t >> 6) & 1;
    const int col = lane & 15, rbase = (lane >> 4) * 4;
    const bool zhalf = n0 < 2048;
#pragma unroll
    for (int i = 0; i < 4; ++i)
#pragma unroll
        for (int j = 0; j < 4; ++j) {
            const int gn = n0 + wn * 64 + j * 16 + col;
            const int gm0 = m0 + wm * 64 + i * 16 + rbase;
            if (zhalf) {
                const float bias = bz[gn];
#pragma unroll
                for (int r = 0; r < 4; ++r) {
                    const size_t idx = (size_t)(gm0 + r) * H_DIM + gn;
                    zout[idx] = sigmoidf_(acc[i][j][r] + bias);
                }
            } else {
                const int gn2 = gn - 2048;
                const float bias = br[gn2];
#pragma unroll
                for (int r = 0; r < 4; ++r) {
                    const size_t idx = (size_t)(gm0 + r) * H_DIM + gn2;
                    const float rt = sigmoidf_(acc[i][j][r] + bias);
                    Arh[(size_t)(gm0 + r) * LDA + gn2] = f2bf(rt * hprev[idx]);
                }
            }
        }
}

// ---------------------------------------------------------------------------
// GEMM 2: A(k-window [x|rh]) @ Bh([Wh;Uh]) -> h_t = (1-z)h + z*tanh(.+bh).
// grid (16, 64).
// ---------------------------------------------------------------------------
__global__ __launch_bounds__(256) void gemm_h(const unsigned short* __restrict__ Axrh,
                                              const unsigned short* __restrict__ Bh,
                                              const float* __restrict__ hprev,
                                              const float* __restrict__ bh,
                                              float* __restrict__ out) {
    __shared__ unsigned short lds[4 * 128 * 32];
    float4v acc[4][4];
#pragma unroll
    for (int i = 0; i < 4; ++i)
#pragma unroll
        for (int j = 0; j < 4; ++j)
            acc[i][j] = (float4v){0.f, 0.f, 0.f, 0.f};

    const int m0 = blockIdx.y * 128;
    const int n0 = blockIdx.x * 128;

    gemm_core(Axrh, Bh, m0, n0, acc, lds);  // K = 4096 = [x | rh]

    const int t = threadIdx.x, lane = t & 63;
    const int wm = (t >> 6) >> 1, wn = (t >> 6) & 1;
    const int col = lane & 15, rbase = (lane >> 4) * 4;
#pragma unroll
    for (int i = 0; i < 4; ++i)
#pragma unroll
        for (int j = 0; j < 4; ++j) {
            const int gn = n0 + wn * 64 + j * 16 + col;
            const int gm0 = m0 + wm * 64 + i * 16 + rbase;
            const float bias = bh[gn];
#pragma unroll
            for (int r = 0; r < 4; ++r) {
                const size_t idx = (size_t)(gm0 + r) * H_DIM + gn;
                const float ht = tanhf(acc[i][j][r] + bias);
                const float z = out[idx];     // z staged here by gemm_zr
                const float h = hprev[idx];
                out[idx] = (1.0f - z) * h + z * ht;
            }
        }
}

// ---------------------------------------------------------------------------
// Workspace (144 MiB):
//   [0,    96MiB)  A    8192 x 6144 bf16 : cols [0,2048)=h16, [2048,4096)=x16,
//                                          [4096,6144)=rh16 (filled by gemm_zr)
//   [96,  128MiB)  Bzr  4096 x 4096 bf16 : rows n:      [UzT(n)|WzT(n)]
//                                          rows 2048+n: [UrT(n)|WrT(n)]
//   [128, 144MiB)  Bh   2048 x 4096 bf16 : rows n: [WhT(n)|UhT(n)]
// ---------------------------------------------------------------------------
extern "C" void kernel_launch(void* const* d_in, const int* in_sizes, int n_in,
                              void* d_out, int out_size, void* d_ws, size_t ws_size,
                              hipStream_t stream) {
    const float* x  = (const float*)d_in[0];
    const float* h  = (const float*)d_in[1];
    const float* Wz = (const float*)d_in[2];
    const float* Wr = (const float*)d_in[3];
    const float* Wh = (const float*)d_in[4];
    const float* Uz = (const float*)d_in[5];
    const float* Ur = (const float*)d_in[6];
    const float* Uh = (const float*)d_in[7];
    const float* bz = (const float*)d_in[8];
    const float* br = (const float*)d_in[9];
    const float* bh = (const float*)d_in[10];
    float* out = (float*)d_out;

    char* ws = (char*)d_ws;
    unsigned short* Abuf = (unsigned short*)(ws);
    unsigned short* Bzr  = (unsigned short*)(ws + (size_t)96  * 1024 * 1024);
    unsigned short* Bh   = (unsigned short*)(ws + (size_t)128 * 1024 * 1024);

    // 1) convert x, h into fused A buffer
    cvt_rows<<<dim3(B_DIM, 1, 2), 256, 0, stream>>>(x, h, Abuf);

    // 2) transpose+convert weights into concatenated-K B buffers
    P6 io;
    io.s[0] = Uz; io.d[0] = Bzr;                                   // rows 0..2047, k 0..2047
    io.s[1] = Wz; io.d[1] = Bzr + 2048;                            // rows 0..2047, k 2048..4095
    io.s[2] = Ur; io.d[2] = Bzr + (size_t)2048 * LDB;              // rows 2048..4095
    io.s[3] = Wr; io.d[3] = Bzr + (size_t)2048 * LDB + 2048;
    io.s[4] = Wh; io.d[4] = Bh;
    io.s[5] = Uh; io.d[5] = Bh + 2048;
    transpose_cvt<<<dim3(32, 32, 6), 256, 0, stream>>>(io);

    // 3) z/r GEMM: M=8192, N=4096, K=4096
    gemm_zr<<<dim3(32, 64), 256, 0, stream>>>(Abuf, Bzr, h, bz, br, out,
                                              Abuf + 4096 /* rh col block */);

    // 4) candidate GEMM + final gate: M=8192, N=2048, K=4096
    gemm_h<<<dim3(16, 64), 256, 0, stream>>>(Abuf + 2048 /* [x|rh] window */,
                                             Bh, h, bh, out);
}